// Round 18
// baseline (841.030 us; speedup 1.0000x reference)
//
#include <hip/hip_runtime.h>
#include <hip/hip_cooperative_groups.h>

namespace cg = cooperative_groups;

// GNN (5 layers sparse msg-passing + dense+relu) -> gather -> concat -> FC over 50000 entities.
// csr_build: ONE cooperative kernel (zero+hist+scan1+scan2+scan3+scatter, grid.sync between
//   phases) replacing 6 dispatches.
// convert_all: tobf16 + wconv + wt in one dispatch.
// layer_fused v2 (measured best) layers 0..3 full-graph; layer 4 head-rows-only fused with
//   the embed gather AND rel-half fill. fc v7 (measured best). 8 dispatches total.

#define N_NODES 50000
#define N_EDGES 800000
#define D 128
#define N_LAYERS 5
#define N_ENT 50000
#define BATCH 1024
#define KDIM 256  // 2*D
#define SCAN_BLOCKS ((N_NODES + 255) / 256)  // 196
#define FC_NT 128  // n-tile per block (wave: 32 n)
#define CSR_GRID 1024  // cooperative grid (4 blocks/CU, co-resident)

// convert_all block-range partition (each range exact multiple of 256 threads)
#define CVT_A_BLOCKS 3125  // entbf: N_NODES*D/8 = 800000 items
#define CVT_B_BLOCKS 320   // Wt5:   N_LAYERS*D*D = 81920 items
#define CVT_C_BLOCKS 6250  // Wt:    N_ENT*KDIM/8 = 1600000 items

typedef __attribute__((ext_vector_type(8))) __bf16 bf16x8;
typedef __attribute__((ext_vector_type(4))) float f32x4;
typedef __attribute__((ext_vector_type(8))) unsigned short u16x8;
typedef __attribute__((ext_vector_type(4))) unsigned short u16x4;

__device__ inline unsigned short f2bf(float x) {
  unsigned int u = __float_as_uint(x);
  unsigned int r = (u + 0x7FFFu + ((u >> 16) & 1u)) >> 16;  // RNE
  return (unsigned short)r;
}
__device__ inline float bf2f(unsigned short b) {
  return __uint_as_float(((unsigned int)b) << 16);
}

__device__ inline int block_exscan256(int v, int* wsum, int* tot) {
  int t = threadIdx.x, lane = t & 63, wid = t >> 6;
  int s = v;
#pragma unroll
  for (int off = 1; off < 64; off <<= 1) {
    int u = __shfl_up(s, off, 64);
    if (lane >= off) s += u;
  }
  if (lane == 63) wsum[wid] = s;
  __syncthreads();
  if (t == 0) {
    int run = 0;
#pragma unroll
    for (int w = 0; w < 4; ++w) { int tmp = wsum[w]; wsum[w] = run; run += tmp; }
    wsum[4] = run;
  }
  __syncthreads();
  *tot = wsum[4];
  return wsum[wid] + s - v;
}

// ONE cooperative kernel: zero -> hist -> scan(3 phases) -> scatter, grid.sync() between.
__global__ __launch_bounds__(256) void csr_build(const int* __restrict__ edge_row,
                                                 const int* __restrict__ edge_col,
                                                 const float* __restrict__ edge_val,
                                                 int* __restrict__ counts,
                                                 int* __restrict__ row_ptr,
                                                 int* __restrict__ cursor,
                                                 int* __restrict__ bsum,
                                                 int* __restrict__ col_s,
                                                 float* __restrict__ val_s) {
  cg::grid_group grid = cg::this_grid();
  __shared__ int wsum[5];
  int t = threadIdx.x;
  int gid = blockIdx.x * 256 + t;
  int gstride = gridDim.x * 256;

  // P0: zero counts
  for (int i = gid; i < N_NODES; i += gstride) counts[i] = 0;
  grid.sync();

  // P1: hist
  for (int i = gid; i < N_EDGES; i += gstride) atomicAdd(&counts[edge_row[i]], 1);
  grid.sync();

  // P2: per-chunk exclusive scan (blocks 0..SCAN_BLOCKS-1)
  if (blockIdx.x < SCAN_BLOCKS) {
    int i = blockIdx.x * 256 + t;
    int v = (i < N_NODES) ? counts[i] : 0;
    int tot;
    int ex = block_exscan256(v, wsum, &tot);
    if (i < N_NODES) row_ptr[i] = ex;
    if (t == 0) bsum[blockIdx.x] = tot;
  }
  grid.sync();

  // P3: scan the chunk totals (block 0 only)
  if (blockIdx.x == 0) {
    int v = (t < SCAN_BLOCKS) ? bsum[t] : 0;
    int tot;
    int ex = block_exscan256(v, wsum, &tot);
    if (t < SCAN_BLOCKS) bsum[t] = ex;
  }
  grid.sync();

  // P4: add chunk offsets; init cursor; write row_ptr[N]
  if (blockIdx.x < SCAN_BLOCKS) {
    int i = blockIdx.x * 256 + t;
    if (i < N_NODES) {
      int ex = row_ptr[i] + bsum[blockIdx.x];
      row_ptr[i] = ex;
      cursor[i] = ex;
      if (i == N_NODES - 1) row_ptr[N_NODES] = ex + counts[i];
    }
  }
  grid.sync();

  // P5: scatter edges into CSR order
  for (int i = gid; i < N_EDGES; i += gstride) {
    int r = edge_row[i];
    int pos = atomicAdd(&cursor[r], 1);
    col_s[pos] = edge_col[i];
    val_s[pos] = edge_val[i];
  }
}

// ONE dispatch for all weight/feature conversions (block-range partitioned, branch-uniform)
__global__ __launch_bounds__(256) void convert_all(const float* __restrict__ entity,
                                                   const float* __restrict__ gW,
                                                   const float* __restrict__ fcW,
                                                   unsigned short* __restrict__ entbf,
                                                   unsigned short* __restrict__ Wt5,
                                                   unsigned short* __restrict__ Wt) {
  int bid = blockIdx.x;
  int t = threadIdx.x;
  if (bid < CVT_A_BLOCKS) {
    int i = bid * 256 + t;  // < 800000 exact
    float4 a = *(const float4*)&entity[i * 8];
    float4 b = *(const float4*)&entity[i * 8 + 4];
    u16x8 o;
    o[0] = f2bf(a.x); o[1] = f2bf(a.y); o[2] = f2bf(a.z); o[3] = f2bf(a.w);
    o[4] = f2bf(b.x); o[5] = f2bf(b.y); o[6] = f2bf(b.z); o[7] = f2bf(b.w);
    *(u16x8*)&entbf[i * 8] = o;
  } else if (bid < CVT_A_BLOCKS + CVT_B_BLOCKS) {
    int idx = (bid - CVT_A_BLOCKS) * 256 + t;  // < 81920 exact
    int l = idx / (D * D);
    int rem = idx - l * D * D;
    int j = rem >> 7;
    int k = rem & 127;
    Wt5[idx] = f2bf(gW[l * D * D + k * D + j]);
  } else {
    int id = (bid - CVT_A_BLOCKS - CVT_B_BLOCKS) * 256 + t;  // < 1600000 exact
    int kg = id / N_ENT;        // 0..31
    int n = id - kg * N_ENT;    // 0..49999
    int k0 = kg * 8;
    u16x8 pk;
#pragma unroll
    for (int e = 0; e < 8; ++e) pk[e] = f2bf(fcW[(size_t)(k0 + e) * N_ENT + n]);
    *(u16x8*)&Wt[(size_t)n * KDIM + k0] = pk;
  }
}

// process up to cnt (<=16) edges whose (col,val) live in this quarter's lanes
__device__ inline void agg_batch(int cl, float vl, int cnt, int q, int l16,
                                 const unsigned short* __restrict__ xb, float* acc) {
  int j = 0;
  for (; j + 4 <= cnt; j += 4) {
    int c[4]; float v[4]; u16x8 xv[4];
#pragma unroll
    for (int u = 0; u < 4; ++u) {
      c[u] = __shfl(cl, q * 16 + j + u);
      v[u] = __shfl(vl, q * 16 + j + u);
    }
#pragma unroll
    for (int u = 0; u < 4; ++u) xv[u] = *(const u16x8*)&xb[c[u] * D + l16 * 8];
#pragma unroll
    for (int u = 0; u < 4; ++u)
#pragma unroll
      for (int dd = 0; dd < 8; ++dd) acc[dd] = fmaf(v[u], bf2f(xv[u][dd]), acc[dd]);
  }
  for (; j < cnt; ++j) {
    int c = __shfl(cl, q * 16 + j);
    float v = __shfl(vl, q * 16 + j);
    u16x8 xv0 = *(const u16x8*)&xb[c * D + l16 * 8];
#pragma unroll
    for (int dd = 0; dd < 8; ++dd) acc[dd] = fmaf(v, bf2f(xv0[dd]), acc[dd]);
  }
}

// Fused GNN layer: block = 64 node rows. READS xb, WRITES yb (distinct buffers!).
__global__ __launch_bounds__(256) void layer_fused(const unsigned short* __restrict__ xb,
                                                   const int* __restrict__ row_ptr,
                                                   const int* __restrict__ cols,
                                                   const float* __restrict__ vals,
                                                   const unsigned short* __restrict__ Bt,  // [j][k]
                                                   const float* __restrict__ bias,
                                                   unsigned short* __restrict__ yb) {
  __shared__ unsigned short atile[64 * D];  // 16 KB; 16B chunks, chunk ^= row&7
  int t = threadIdx.x, lane = t & 63, wave = t >> 6;
  int q = lane >> 4, l16 = lane & 15;
  int r0 = blockIdx.x * 64;
  char* ab = (char*)atile;

#pragma unroll
  for (int p = 0; p < 4; ++p) {
    int row_l = wave * 16 + p * 4 + q;
    int r = r0 + row_l;
    float acc[8] = {0.f, 0.f, 0.f, 0.f, 0.f, 0.f, 0.f, 0.f};
    if (r < N_NODES) {
      int e0 = row_ptr[r], e1 = row_ptr[r + 1];
      for (int base = e0; base < e1; base += 16) {
        int idx = base + l16;
        bool ok = idx < e1;
        int cl = ok ? cols[idx] : 0;
        float vl = ok ? vals[idx] : 0.f;
        agg_batch(cl, vl, min(16, e1 - base), q, l16, xb, acc);
      }
    }
    u16x8 o;
#pragma unroll
    for (int dd = 0; dd < 8; ++dd) o[dd] = f2bf(acc[dd]);
    *(u16x8*)(ab + row_l * 256 + ((l16 ^ (row_l & 7)) << 4)) = o;
  }
  __syncthreads();

  int lq = lane >> 4;
  f32x4 acc2[4][2];
#pragma unroll
  for (int m = 0; m < 4; ++m) { acc2[m][0] = (f32x4){0,0,0,0}; acc2[m][1] = (f32x4){0,0,0,0}; }
#pragma unroll
  for (int kk = 0; kk < 4; ++kk) {
    bf16x8 wfr[2];
#pragma unroll
    for (int nt = 0; nt < 2; ++nt)
      wfr[nt] = *(const bf16x8*)&Bt[(wave * 32 + nt * 16 + l16) * D + kk * 32 + lq * 8];
#pragma unroll
    for (int m = 0; m < 4; ++m) {
      int row_l = m * 16 + l16;
      bf16x8 afr = *(const bf16x8*)(ab + row_l * 256 + ((((kk * 4 + lq) ^ (row_l & 7)) << 4)));
      acc2[m][0] = __builtin_amdgcn_mfma_f32_16x16x32_bf16(wfr[0], afr, acc2[m][0], 0, 0, 0);
      acc2[m][1] = __builtin_amdgcn_mfma_f32_16x16x32_bf16(wfr[1], afr, acc2[m][1], 0, 0, 0);
    }
  }
#pragma unroll
  for (int nt = 0; nt < 2; ++nt) {
    int jb = wave * 32 + nt * 16 + lq * 4;
    float4 bb = *(const float4*)&bias[jb];
#pragma unroll
    for (int m = 0; m < 4; ++m) {
      int r = r0 + m * 16 + l16;
      if (r < N_NODES) {
        u16x4 o;
        o[0] = f2bf(fmaxf(acc2[m][nt][0] + bb.x, 0.f));
        o[1] = f2bf(fmaxf(acc2[m][nt][1] + bb.y, 0.f));
        o[2] = f2bf(fmaxf(acc2[m][nt][2] + bb.z, 0.f));
        o[3] = f2bf(fmaxf(acc2[m][nt][3] + bb.w, 0.f));
        *(u16x4*)&yb[(size_t)r * D + jb] = o;
      }
    }
  }
}

// Last GNN layer, HEAD ROWS ONLY + rel-half fill: block = 64 batch rows (16 blocks).
__global__ __launch_bounds__(256) void layer_head(const unsigned short* __restrict__ xb,
                                                  const int* __restrict__ row_ptr,
                                                  const int* __restrict__ cols,
                                                  const float* __restrict__ vals,
                                                  const int* __restrict__ head_idx,
                                                  const float* __restrict__ rel_table,
                                                  const int* __restrict__ rel_ids,
                                                  const unsigned short* __restrict__ Bt,
                                                  const float* __restrict__ bias,
                                                  unsigned short* __restrict__ ebf) {
  __shared__ unsigned short atile[64 * D];
  int t = threadIdx.x, lane = t & 63, wave = t >> 6;
  int q = lane >> 4, l16 = lane & 15;
  int r0 = blockIdx.x * 64;
  char* ab = (char*)atile;

  // rel half: 64 rows x 128 cols, 1024 8-elem chunks over 256 threads
#pragma unroll
  for (int it = 0; it < 4; ++it) {
    int c = it * 256 + t;
    int bl = c >> 4;
    int kq = c & 15;
    int b = r0 + bl;
    const float* rp = &rel_table[(size_t)rel_ids[b] * D + kq * 8];
    float4 a0 = *(const float4*)rp;
    float4 a1 = *(const float4*)(rp + 4);
    u16x8 o;
    o[0] = f2bf(a0.x); o[1] = f2bf(a0.y); o[2] = f2bf(a0.z); o[3] = f2bf(a0.w);
    o[4] = f2bf(a1.x); o[5] = f2bf(a1.y); o[6] = f2bf(a1.z); o[7] = f2bf(a1.w);
    *(u16x8*)&ebf[(size_t)b * KDIM + D + kq * 8] = o;
  }

#pragma unroll
  for (int p = 0; p < 4; ++p) {
    int row_l = wave * 16 + p * 4 + q;
    int b = r0 + row_l;
    int r = head_idx[b];
    float acc[8] = {0.f, 0.f, 0.f, 0.f, 0.f, 0.f, 0.f, 0.f};
    int e0 = row_ptr[r], e1 = row_ptr[r + 1];
    for (int base = e0; base < e1; base += 16) {
      int idx = base + l16;
      bool ok = idx < e1;
      int cl = ok ? cols[idx] : 0;
      float vl = ok ? vals[idx] : 0.f;
      agg_batch(cl, vl, min(16, e1 - base), q, l16, xb, acc);
    }
    u16x8 o;
#pragma unroll
    for (int dd = 0; dd < 8; ++dd) o[dd] = f2bf(acc[dd]);
    *(u16x8*)(ab + row_l * 256 + ((l16 ^ (row_l & 7)) << 4)) = o;
  }
  __syncthreads();

  int lq = lane >> 4;
  f32x4 acc2[4][2];
#pragma unroll
  for (int m = 0; m < 4; ++m) { acc2[m][0] = (f32x4){0,0,0,0}; acc2[m][1] = (f32x4){0,0,0,0}; }
#pragma unroll
  for (int kk = 0; kk < 4; ++kk) {
    bf16x8 wfr[2];
#pragma unroll
    for (int nt = 0; nt < 2; ++nt)
      wfr[nt] = *(const bf16x8*)&Bt[(wave * 32 + nt * 16 + l16) * D + kk * 32 + lq * 8];
#pragma unroll
    for (int m = 0; m < 4; ++m) {
      int row_l = m * 16 + l16;
      bf16x8 afr = *(const bf16x8*)(ab + row_l * 256 + ((((kk * 4 + lq) ^ (row_l & 7)) << 4)));
      acc2[m][0] = __builtin_amdgcn_mfma_f32_16x16x32_bf16(wfr[0], afr, acc2[m][0], 0, 0, 0);
      acc2[m][1] = __builtin_amdgcn_mfma_f32_16x16x32_bf16(wfr[1], afr, acc2[m][1], 0, 0, 0);
    }
  }
#pragma unroll
  for (int nt = 0; nt < 2; ++nt) {
    int jb = wave * 32 + nt * 16 + lq * 4;
    float4 bb = *(const float4*)&bias[jb];
#pragma unroll
    for (int m = 0; m < 4; ++m) {
      int b = r0 + m * 16 + l16;
      u16x4 o;
      o[0] = f2bf(fmaxf(acc2[m][nt][0] + bb.x, 0.f));
      o[1] = f2bf(fmaxf(acc2[m][nt][1] + bb.y, 0.f));
      o[2] = f2bf(fmaxf(acc2[m][nt][2] + bb.z, 0.f));
      o[3] = f2bf(fmaxf(acc2[m][nt][3] + bb.w, 0.f));
      *(u16x4*)&ebf[(size_t)b * KDIM + jb] = o;
    }
  }
}

// FC: out[b][n] = sum_k ebf[b][k]*Wt[n][k] + fcb[n]   [round-13 measured-best version]
__global__ __launch_bounds__(256, 2) void fc_mfma(const unsigned short* __restrict__ ebf,
                                                  const unsigned short* __restrict__ Wt,
                                                  const float* __restrict__ fcb,
                                                  float* __restrict__ out) {
  __shared__ unsigned short etile[64 * KDIM];  // 32 KB
  int t = threadIdx.x;
  int lane = t & 63, wave = t >> 6;
  int l16 = lane & 15, lq = lane >> 4;
  int n0 = blockIdx.x * FC_NT;
  char* eb = (char*)etile;

  bf16x8 afr[2][8];
#pragma unroll
  for (int nt = 0; nt < 2; ++nt) {
    const unsigned short* wp = Wt + (size_t)(n0 + wave * 32 + nt * 16 + l16) * KDIM + lq * 8;
#pragma unroll
    for (int kk = 0; kk < 8; ++kk) afr[nt][kk] = *(const bf16x8*)(wp + kk * 32);
  }

  int n_st[2]; float4 bv[2];
#pragma unroll
  for (int nt = 0; nt < 2; ++nt) {
    n_st[nt] = n0 + wave * 32 + nt * 16 + lq * 4;
    bv[nt] = make_float4(0.f, 0.f, 0.f, 0.f);
    if (n_st[nt] < N_ENT) bv[nt] = *(const float4*)&fcb[n_st[nt]];
  }

  for (int bc = 0; bc < 8; ++bc) {
    int b0 = blockIdx.y * 512 + bc * 64;
    const char* esrc = (const char*)(ebf + (size_t)b0 * KDIM);
#pragma unroll
    for (int it = 0; it < 8; ++it) {
      int c = it * 256 + t;
      int row = c >> 5;
      int ci = c & 31;
      float4 v = *(const float4*)(esrc + (size_t)c * 16);
      *(float4*)(eb + row * 512 + ((ci ^ ((row & 7) << 2)) << 4)) = v;
    }
    __syncthreads();

    f32x4 acc[2][4];
#pragma unroll
    for (int nt = 0; nt < 2; ++nt)
#pragma unroll
      for (int m = 0; m < 4; ++m) acc[nt][m] = (f32x4){0.f, 0.f, 0.f, 0.f};

#pragma unroll
    for (int m = 0; m < 4; ++m) {
      int row = m * 16 + l16;
#pragma unroll
      for (int kk = 0; kk < 8; ++kk) {
        bf16x8 bfr = *(const bf16x8*)(eb + row * 512 + ((((kk * 4 + lq) ^ ((row & 7) << 2)) << 4)));
        acc[0][m] = __builtin_amdgcn_mfma_f32_16x16x32_bf16(afr[0][kk], bfr, acc[0][m], 0, 0, 0);
        acc[1][m] = __builtin_amdgcn_mfma_f32_16x16x32_bf16(afr[1][kk], bfr, acc[1][m], 0, 0, 0);
      }
    }

#pragma unroll
    for (int nt = 0; nt < 2; ++nt) {
      if (n_st[nt] < N_ENT) {
#pragma unroll
        for (int m = 0; m < 4; ++m) {
          int b = b0 + m * 16 + l16;
          float4 o = {acc[nt][m][0] + bv[nt].x, acc[nt][m][1] + bv[nt].y,
                      acc[nt][m][2] + bv[nt].z, acc[nt][m][3] + bv[nt].w};
          *(float4*)&out[(size_t)b * N_ENT + n_st[nt]] = o;
        }
      }
    }
    __syncthreads();
  }
}

extern "C" void kernel_launch(void* const* d_in, const int* in_sizes, int n_in,
                              void* d_out, int out_size, void* d_ws, size_t ws_size,
                              hipStream_t stream) {
  const float* entity    = (const float*)d_in[0];
  const float* edge_val  = (const float*)d_in[1];
  const float* gnn_W     = (const float*)d_in[2];
  const float* gnn_b     = (const float*)d_in[3];
  const float* rel_table = (const float*)d_in[4];
  const float* fc_W      = (const float*)d_in[5];
  const float* fc_b      = (const float*)d_in[6];
  const int* edge_row    = (const int*)d_in[7];
  const int* edge_col    = (const int*)d_in[8];
  const int* head_idx    = (const int*)d_in[9];
  const int* rel_ids     = (const int*)d_in[10];
  float* out = (float*)d_out;

  char* ws = (char*)d_ws;
  size_t off = 0;
  auto alloc = [&](size_t bytes) -> void* {
    void* p = ws + off;
    off = (off + bytes + 255) & ~(size_t)255;
    return p;
  };
  int* counts   = (int*)alloc((size_t)N_NODES * 4);
  int* row_ptr  = (int*)alloc((size_t)(N_NODES + 1) * 4);
  int* cursor   = (int*)alloc((size_t)N_NODES * 4);
  int* bsum     = (int*)alloc((size_t)256 * 4);
  int* col_s    = (int*)alloc((size_t)N_EDGES * 4);
  float* val_s  = (float*)alloc((size_t)N_EDGES * 4);
  unsigned short* xA    = (unsigned short*)alloc((size_t)N_NODES * D * 2);
  unsigned short* xB    = (unsigned short*)alloc((size_t)N_NODES * D * 2);
  unsigned short* entbf = (unsigned short*)alloc((size_t)N_NODES * D * 2);
  unsigned short* ebf   = (unsigned short*)alloc((size_t)BATCH * KDIM * 2);
  unsigned short* Wt    = (unsigned short*)alloc((size_t)(N_ENT + 256) * KDIM * 2);  // pad rows
  unsigned short* Wt5   = (unsigned short*)alloc((size_t)N_LAYERS * D * D * 2);

  // CSR build: one cooperative kernel (zero+hist+scan+scatter with grid.sync)
  {
    void* args[] = {(void*)&edge_row, (void*)&edge_col, (void*)&edge_val,
                    (void*)&counts, (void*)&row_ptr, (void*)&cursor,
                    (void*)&bsum, (void*)&col_s, (void*)&val_s};
    hipLaunchCooperativeKernel((const void*)csr_build, dim3(CSR_GRID), dim3(256),
                               args, 0, stream);
  }

  // all conversions in one dispatch
  convert_all<<<CVT_A_BLOCKS + CVT_B_BLOCKS + CVT_C_BLOCKS, 256, 0, stream>>>(
      entity, gnn_W, fc_W, entbf, Wt5, Wt);

  // layers 0..3 full-graph, ping-pong: entbf->xA, xA->xB, xB->xA, xA->xB
  for (int layer = 0; layer < N_LAYERS - 1; ++layer) {
    const unsigned short* xin = (layer == 0) ? entbf : ((layer & 1) ? xA : xB);
    unsigned short* yout = (layer & 1) ? xB : xA;
    layer_fused<<<(N_NODES + 63) / 64, 256, 0, stream>>>(xin, row_ptr, col_s, val_s,
                                                         Wt5 + (size_t)layer * D * D,
                                                         gnn_b + (size_t)layer * D, yout);
  }

  // layer 4 head-rows-only + rel fill, fused: reads xB (layer-3 out), writes full ebf
  layer_head<<<BATCH / 64, 256, 0, stream>>>(xB, row_ptr, col_s, val_s, head_idx,
                                             rel_table, rel_ids,
                                             Wt5 + (size_t)(N_LAYERS - 1) * D * D,
                                             gnn_b + (size_t)(N_LAYERS - 1) * D, ebf);

  // FC: grid (n-tiles, b-halves)
  dim3 fcg((N_ENT + FC_NT - 1) / FC_NT, 2);
  fc_mfma<<<fcg, 256, 0, stream>>>(ebf, Wt, fc_b, out);
}

// Round 19
// 377.160 us; speedup vs baseline: 2.2299x; 2.2299x over previous
//
#include <hip/hip_runtime.h>

// GNN (5 layers sparse msg-passing + dense+relu) -> gather -> concat -> FC over 50000 entities.
// CSR build: memset + hist + scan1 + scan3(self-offset) + scatter (no coop kernels —
//   round-18 lesson: grid.sync costs ~100us/barrier on 8-XCD MI355X; stream boundaries ~4us).
// convert_all: tobf16 + wconv + wt in one dispatch.
// layer_fused v2 (measured best) layers 0..3 full-graph; layer 4 head-rows-only fused with
//   the embed gather AND rel-half fill. fc v7 (measured best). 11 dispatches total.

#define N_NODES 50000
#define N_EDGES 800000
#define D 128
#define N_LAYERS 5
#define N_ENT 50000
#define BATCH 1024
#define KDIM 256  // 2*D
#define SCAN_BLOCKS ((N_NODES + 255) / 256)  // 196
#define FC_NT 128  // n-tile per block (wave: 32 n)

// convert_all block-range partition (each range exact multiple of 256 threads)
#define CVT_A_BLOCKS 3125  // entbf: N_NODES*D/8 = 800000 items
#define CVT_B_BLOCKS 320   // Wt5:   N_LAYERS*D*D = 81920 items
#define CVT_C_BLOCKS 6250  // Wt:    N_ENT*KDIM/8 = 1600000 items

typedef __attribute__((ext_vector_type(8))) __bf16 bf16x8;
typedef __attribute__((ext_vector_type(4))) float f32x4;
typedef __attribute__((ext_vector_type(8))) unsigned short u16x8;
typedef __attribute__((ext_vector_type(4))) unsigned short u16x4;

__device__ inline unsigned short f2bf(float x) {
  unsigned int u = __float_as_uint(x);
  unsigned int r = (u + 0x7FFFu + ((u >> 16) & 1u)) >> 16;  // RNE
  return (unsigned short)r;
}
__device__ inline float bf2f(unsigned short b) {
  return __uint_as_float(((unsigned int)b) << 16);
}

__global__ void hist_kernel(const int* __restrict__ rows, int* __restrict__ counts) {
  int i = blockIdx.x * blockDim.x + threadIdx.x;
  int stride = gridDim.x * blockDim.x;
  for (; i < N_EDGES; i += stride) atomicAdd(&counts[rows[i]], 1);
}

__device__ inline int block_exscan256(int v, int* wsum, int* tot) {
  int t = threadIdx.x, lane = t & 63, wid = t >> 6;
  int s = v;
#pragma unroll
  for (int off = 1; off < 64; off <<= 1) {
    int u = __shfl_up(s, off, 64);
    if (lane >= off) s += u;
  }
  if (lane == 63) wsum[wid] = s;
  __syncthreads();
  if (t == 0) {
    int run = 0;
#pragma unroll
    for (int w = 0; w < 4; ++w) { int tmp = wsum[w]; wsum[w] = run; run += tmp; }
    wsum[4] = run;
  }
  __syncthreads();
  *tot = wsum[4];
  return wsum[wid] + s - v;
}

__global__ __launch_bounds__(256) void scan1_kernel(const int* __restrict__ counts,
                                                    int* __restrict__ row_ptr,
                                                    int* __restrict__ bsum) {
  __shared__ int wsum[5];
  int i = blockIdx.x * 256 + threadIdx.x;
  int v = (i < N_NODES) ? counts[i] : 0;
  int tot;
  int ex = block_exscan256(v, wsum, &tot);
  if (i < N_NODES) row_ptr[i] = ex;
  if (threadIdx.x == 0) bsum[blockIdx.x] = tot;
}

// scan3 with self-computed offset: offset = sum(bsum[0..bid)) via in-block reduction.
// (folds the old single-block scan2 into every block — 196 extra loads/block, trivial)
__global__ __launch_bounds__(256) void scan3_kernel(const int* __restrict__ counts,
                                                    const int* __restrict__ bsum,
                                                    int* __restrict__ row_ptr,
                                                    int* __restrict__ cursor) {
  __shared__ int wred[4];
  int t = threadIdx.x, lane = t & 63, wid = t >> 6;
  int bid = blockIdx.x;
  int v = (t < SCAN_BLOCKS && t < bid) ? bsum[t] : 0;
#pragma unroll
  for (int off = 32; off > 0; off >>= 1) v += __shfl_down(v, off, 64);
  if (lane == 0) wred[wid] = v;
  __syncthreads();
  int offset = wred[0] + wred[1] + wred[2] + wred[3];
  int i = bid * 256 + t;
  if (i >= N_NODES) return;
  int ex = row_ptr[i] + offset;
  row_ptr[i] = ex;
  cursor[i] = ex;
  if (i == N_NODES - 1) row_ptr[N_NODES] = ex + counts[i];
}

__global__ void scatter_kernel(const int* __restrict__ rows, const int* __restrict__ cols,
                               const float* __restrict__ vals, int* __restrict__ cursor,
                               int* __restrict__ col_s, float* __restrict__ val_s) {
  int i = blockIdx.x * blockDim.x + threadIdx.x;
  int stride = gridDim.x * blockDim.x;
  for (; i < N_EDGES; i += stride) {
    int r = rows[i];
    int pos = atomicAdd(&cursor[r], 1);
    col_s[pos] = cols[i];
    val_s[pos] = vals[i];
  }
}

// ONE dispatch for all weight/feature conversions (block-range partitioned, branch-uniform)
__global__ __launch_bounds__(256) void convert_all(const float* __restrict__ entity,
                                                   const float* __restrict__ gW,
                                                   const float* __restrict__ fcW,
                                                   unsigned short* __restrict__ entbf,
                                                   unsigned short* __restrict__ Wt5,
                                                   unsigned short* __restrict__ Wt) {
  int bid = blockIdx.x;
  int t = threadIdx.x;
  if (bid < CVT_A_BLOCKS) {
    int i = bid * 256 + t;  // < 800000 exact
    float4 a = *(const float4*)&entity[i * 8];
    float4 b = *(const float4*)&entity[i * 8 + 4];
    u16x8 o;
    o[0] = f2bf(a.x); o[1] = f2bf(a.y); o[2] = f2bf(a.z); o[3] = f2bf(a.w);
    o[4] = f2bf(b.x); o[5] = f2bf(b.y); o[6] = f2bf(b.z); o[7] = f2bf(b.w);
    *(u16x8*)&entbf[i * 8] = o;
  } else if (bid < CVT_A_BLOCKS + CVT_B_BLOCKS) {
    int idx = (bid - CVT_A_BLOCKS) * 256 + t;  // < 81920 exact
    int l = idx / (D * D);
    int rem = idx - l * D * D;
    int j = rem >> 7;
    int k = rem & 127;
    Wt5[idx] = f2bf(gW[l * D * D + k * D + j]);
  } else {
    int id = (bid - CVT_A_BLOCKS - CVT_B_BLOCKS) * 256 + t;  // < 1600000 exact
    int kg = id / N_ENT;        // 0..31
    int n = id - kg * N_ENT;    // 0..49999
    int k0 = kg * 8;
    u16x8 pk;
#pragma unroll
    for (int e = 0; e < 8; ++e) pk[e] = f2bf(fcW[(size_t)(k0 + e) * N_ENT + n]);
    *(u16x8*)&Wt[(size_t)n * KDIM + k0] = pk;
  }
}

// process up to cnt (<=16) edges whose (col,val) live in this quarter's lanes
__device__ inline void agg_batch(int cl, float vl, int cnt, int q, int l16,
                                 const unsigned short* __restrict__ xb, float* acc) {
  int j = 0;
  for (; j + 4 <= cnt; j += 4) {
    int c[4]; float v[4]; u16x8 xv[4];
#pragma unroll
    for (int u = 0; u < 4; ++u) {
      c[u] = __shfl(cl, q * 16 + j + u);
      v[u] = __shfl(vl, q * 16 + j + u);
    }
#pragma unroll
    for (int u = 0; u < 4; ++u) xv[u] = *(const u16x8*)&xb[c[u] * D + l16 * 8];
#pragma unroll
    for (int u = 0; u < 4; ++u)
#pragma unroll
      for (int dd = 0; dd < 8; ++dd) acc[dd] = fmaf(v[u], bf2f(xv[u][dd]), acc[dd]);
  }
  for (; j < cnt; ++j) {
    int c = __shfl(cl, q * 16 + j);
    float v = __shfl(vl, q * 16 + j);
    u16x8 xv0 = *(const u16x8*)&xb[c * D + l16 * 8];
#pragma unroll
    for (int dd = 0; dd < 8; ++dd) acc[dd] = fmaf(v, bf2f(xv0[dd]), acc[dd]);
  }
}

// Fused GNN layer: block = 64 node rows. READS xb, WRITES yb (distinct buffers!).
__global__ __launch_bounds__(256) void layer_fused(const unsigned short* __restrict__ xb,
                                                   const int* __restrict__ row_ptr,
                                                   const int* __restrict__ cols,
                                                   const float* __restrict__ vals,
                                                   const unsigned short* __restrict__ Bt,  // [j][k]
                                                   const float* __restrict__ bias,
                                                   unsigned short* __restrict__ yb) {
  __shared__ unsigned short atile[64 * D];  // 16 KB; 16B chunks, chunk ^= row&7
  int t = threadIdx.x, lane = t & 63, wave = t >> 6;
  int q = lane >> 4, l16 = lane & 15;
  int r0 = blockIdx.x * 64;
  char* ab = (char*)atile;

#pragma unroll
  for (int p = 0; p < 4; ++p) {
    int row_l = wave * 16 + p * 4 + q;
    int r = r0 + row_l;
    float acc[8] = {0.f, 0.f, 0.f, 0.f, 0.f, 0.f, 0.f, 0.f};
    if (r < N_NODES) {
      int e0 = row_ptr[r], e1 = row_ptr[r + 1];
      for (int base = e0; base < e1; base += 16) {
        int idx = base + l16;
        bool ok = idx < e1;
        int cl = ok ? cols[idx] : 0;
        float vl = ok ? vals[idx] : 0.f;
        agg_batch(cl, vl, min(16, e1 - base), q, l16, xb, acc);
      }
    }
    u16x8 o;
#pragma unroll
    for (int dd = 0; dd < 8; ++dd) o[dd] = f2bf(acc[dd]);
    *(u16x8*)(ab + row_l * 256 + ((l16 ^ (row_l & 7)) << 4)) = o;
  }
  __syncthreads();

  int lq = lane >> 4;
  f32x4 acc2[4][2];
#pragma unroll
  for (int m = 0; m < 4; ++m) { acc2[m][0] = (f32x4){0,0,0,0}; acc2[m][1] = (f32x4){0,0,0,0}; }
#pragma unroll
  for (int kk = 0; kk < 4; ++kk) {
    bf16x8 wfr[2];
#pragma unroll
    for (int nt = 0; nt < 2; ++nt)
      wfr[nt] = *(const bf16x8*)&Bt[(wave * 32 + nt * 16 + l16) * D + kk * 32 + lq * 8];
#pragma unroll
    for (int m = 0; m < 4; ++m) {
      int row_l = m * 16 + l16;
      bf16x8 afr = *(const bf16x8*)(ab + row_l * 256 + ((((kk * 4 + lq) ^ (row_l & 7)) << 4)));
      acc2[m][0] = __builtin_amdgcn_mfma_f32_16x16x32_bf16(wfr[0], afr, acc2[m][0], 0, 0, 0);
      acc2[m][1] = __builtin_amdgcn_mfma_f32_16x16x32_bf16(wfr[1], afr, acc2[m][1], 0, 0, 0);
    }
  }
#pragma unroll
  for (int nt = 0; nt < 2; ++nt) {
    int jb = wave * 32 + nt * 16 + lq * 4;
    float4 bb = *(const float4*)&bias[jb];
#pragma unroll
    for (int m = 0; m < 4; ++m) {
      int r = r0 + m * 16 + l16;
      if (r < N_NODES) {
        u16x4 o;
        o[0] = f2bf(fmaxf(acc2[m][nt][0] + bb.x, 0.f));
        o[1] = f2bf(fmaxf(acc2[m][nt][1] + bb.y, 0.f));
        o[2] = f2bf(fmaxf(acc2[m][nt][2] + bb.z, 0.f));
        o[3] = f2bf(fmaxf(acc2[m][nt][3] + bb.w, 0.f));
        *(u16x4*)&yb[(size_t)r * D + jb] = o;
      }
    }
  }
}

// Last GNN layer, HEAD ROWS ONLY + rel-half fill: block = 64 batch rows (16 blocks).
__global__ __launch_bounds__(256) void layer_head(const unsigned short* __restrict__ xb,
                                                  const int* __restrict__ row_ptr,
                                                  const int* __restrict__ cols,
                                                  const float* __restrict__ vals,
                                                  const int* __restrict__ head_idx,
                                                  const float* __restrict__ rel_table,
                                                  const int* __restrict__ rel_ids,
                                                  const unsigned short* __restrict__ Bt,
                                                  const float* __restrict__ bias,
                                                  unsigned short* __restrict__ ebf) {
  __shared__ unsigned short atile[64 * D];
  int t = threadIdx.x, lane = t & 63, wave = t >> 6;
  int q = lane >> 4, l16 = lane & 15;
  int r0 = blockIdx.x * 64;
  char* ab = (char*)atile;

  // rel half: 64 rows x 128 cols, 1024 8-elem chunks over 256 threads
#pragma unroll
  for (int it = 0; it < 4; ++it) {
    int c = it * 256 + t;
    int bl = c >> 4;
    int kq = c & 15;
    int b = r0 + bl;
    const float* rp = &rel_table[(size_t)rel_ids[b] * D + kq * 8];
    float4 a0 = *(const float4*)rp;
    float4 a1 = *(const float4*)(rp + 4);
    u16x8 o;
    o[0] = f2bf(a0.x); o[1] = f2bf(a0.y); o[2] = f2bf(a0.z); o[3] = f2bf(a0.w);
    o[4] = f2bf(a1.x); o[5] = f2bf(a1.y); o[6] = f2bf(a1.z); o[7] = f2bf(a1.w);
    *(u16x8*)&ebf[(size_t)b * KDIM + D + kq * 8] = o;
  }

#pragma unroll
  for (int p = 0; p < 4; ++p) {
    int row_l = wave * 16 + p * 4 + q;
    int b = r0 + row_l;
    int r = head_idx[b];
    float acc[8] = {0.f, 0.f, 0.f, 0.f, 0.f, 0.f, 0.f, 0.f};
    int e0 = row_ptr[r], e1 = row_ptr[r + 1];
    for (int base = e0; base < e1; base += 16) {
      int idx = base + l16;
      bool ok = idx < e1;
      int cl = ok ? cols[idx] : 0;
      float vl = ok ? vals[idx] : 0.f;
      agg_batch(cl, vl, min(16, e1 - base), q, l16, xb, acc);
    }
    u16x8 o;
#pragma unroll
    for (int dd = 0; dd < 8; ++dd) o[dd] = f2bf(acc[dd]);
    *(u16x8*)(ab + row_l * 256 + ((l16 ^ (row_l & 7)) << 4)) = o;
  }
  __syncthreads();

  int lq = lane >> 4;
  f32x4 acc2[4][2];
#pragma unroll
  for (int m = 0; m < 4; ++m) { acc2[m][0] = (f32x4){0,0,0,0}; acc2[m][1] = (f32x4){0,0,0,0}; }
#pragma unroll
  for (int kk = 0; kk < 4; ++kk) {
    bf16x8 wfr[2];
#pragma unroll
    for (int nt = 0; nt < 2; ++nt)
      wfr[nt] = *(const bf16x8*)&Bt[(wave * 32 + nt * 16 + l16) * D + kk * 32 + lq * 8];
#pragma unroll
    for (int m = 0; m < 4; ++m) {
      int row_l = m * 16 + l16;
      bf16x8 afr = *(const bf16x8*)(ab + row_l * 256 + ((((kk * 4 + lq) ^ (row_l & 7)) << 4)));
      acc2[m][0] = __builtin_amdgcn_mfma_f32_16x16x32_bf16(wfr[0], afr, acc2[m][0], 0, 0, 0);
      acc2[m][1] = __builtin_amdgcn_mfma_f32_16x16x32_bf16(wfr[1], afr, acc2[m][1], 0, 0, 0);
    }
  }
#pragma unroll
  for (int nt = 0; nt < 2; ++nt) {
    int jb = wave * 32 + nt * 16 + lq * 4;
    float4 bb = *(const float4*)&bias[jb];
#pragma unroll
    for (int m = 0; m < 4; ++m) {
      int b = r0 + m * 16 + l16;
      u16x4 o;
      o[0] = f2bf(fmaxf(acc2[m][nt][0] + bb.x, 0.f));
      o[1] = f2bf(fmaxf(acc2[m][nt][1] + bb.y, 0.f));
      o[2] = f2bf(fmaxf(acc2[m][nt][2] + bb.z, 0.f));
      o[3] = f2bf(fmaxf(acc2[m][nt][3] + bb.w, 0.f));
      *(u16x4*)&ebf[(size_t)b * KDIM + jb] = o;
    }
  }
}

// FC: out[b][n] = sum_k ebf[b][k]*Wt[n][k] + fcb[n]   [round-13 measured-best version]
__global__ __launch_bounds__(256, 2) void fc_mfma(const unsigned short* __restrict__ ebf,
                                                  const unsigned short* __restrict__ Wt,
                                                  const float* __restrict__ fcb,
                                                  float* __restrict__ out) {
  __shared__ unsigned short etile[64 * KDIM];  // 32 KB
  int t = threadIdx.x;
  int lane = t & 63, wave = t >> 6;
  int l16 = lane & 15, lq = lane >> 4;
  int n0 = blockIdx.x * FC_NT;
  char* eb = (char*)etile;

  bf16x8 afr[2][8];
#pragma unroll
  for (int nt = 0; nt < 2; ++nt) {
    const unsigned short* wp = Wt + (size_t)(n0 + wave * 32 + nt * 16 + l16) * KDIM + lq * 8;
#pragma unroll
    for (int kk = 0; kk < 8; ++kk) afr[nt][kk] = *(const bf16x8*)(wp + kk * 32);
  }

  int n_st[2]; float4 bv[2];
#pragma unroll
  for (int nt = 0; nt < 2; ++nt) {
    n_st[nt] = n0 + wave * 32 + nt * 16 + lq * 4;
    bv[nt] = make_float4(0.f, 0.f, 0.f, 0.f);
    if (n_st[nt] < N_ENT) bv[nt] = *(const float4*)&fcb[n_st[nt]];
  }

  for (int bc = 0; bc < 8; ++bc) {
    int b0 = blockIdx.y * 512 + bc * 64;
    const char* esrc = (const char*)(ebf + (size_t)b0 * KDIM);
#pragma unroll
    for (int it = 0; it < 8; ++it) {
      int c = it * 256 + t;
      int row = c >> 5;
      int ci = c & 31;
      float4 v = *(const float4*)(esrc + (size_t)c * 16);
      *(float4*)(eb + row * 512 + ((ci ^ ((row & 7) << 2)) << 4)) = v;
    }
    __syncthreads();

    f32x4 acc[2][4];
#pragma unroll
    for (int nt = 0; nt < 2; ++nt)
#pragma unroll
      for (int m = 0; m < 4; ++m) acc[nt][m] = (f32x4){0.f, 0.f, 0.f, 0.f};

#pragma unroll
    for (int m = 0; m < 4; ++m) {
      int row = m * 16 + l16;
#pragma unroll
      for (int kk = 0; kk < 8; ++kk) {
        bf16x8 bfr = *(const bf16x8*)(eb + row * 512 + ((((kk * 4 + lq) ^ ((row & 7) << 2)) << 4)));
        acc[0][m] = __builtin_amdgcn_mfma_f32_16x16x32_bf16(afr[0][kk], bfr, acc[0][m], 0, 0, 0);
        acc[1][m] = __builtin_amdgcn_mfma_f32_16x16x32_bf16(afr[1][kk], bfr, acc[1][m], 0, 0, 0);
      }
    }

#pragma unroll
    for (int nt = 0; nt < 2; ++nt) {
      if (n_st[nt] < N_ENT) {
#pragma unroll
        for (int m = 0; m < 4; ++m) {
          int b = b0 + m * 16 + l16;
          float4 o = {acc[nt][m][0] + bv[nt].x, acc[nt][m][1] + bv[nt].y,
                      acc[nt][m][2] + bv[nt].z, acc[nt][m][3] + bv[nt].w};
          *(float4*)&out[(size_t)b * N_ENT + n_st[nt]] = o;
        }
      }
    }
    __syncthreads();
  }
}

extern "C" void kernel_launch(void* const* d_in, const int* in_sizes, int n_in,
                              void* d_out, int out_size, void* d_ws, size_t ws_size,
                              hipStream_t stream) {
  const float* entity    = (const float*)d_in[0];
  const float* edge_val  = (const float*)d_in[1];
  const float* gnn_W     = (const float*)d_in[2];
  const float* gnn_b     = (const float*)d_in[3];
  const float* rel_table = (const float*)d_in[4];
  const float* fc_W      = (const float*)d_in[5];
  const float* fc_b      = (const float*)d_in[6];
  const int* edge_row    = (const int*)d_in[7];
  const int* edge_col    = (const int*)d_in[8];
  const int* head_idx    = (const int*)d_in[9];
  const int* rel_ids     = (const int*)d_in[10];
  float* out = (float*)d_out;

  char* ws = (char*)d_ws;
  size_t off = 0;
  auto alloc = [&](size_t bytes) -> void* {
    void* p = ws + off;
    off = (off + bytes + 255) & ~(size_t)255;
    return p;
  };
  int* counts   = (int*)alloc((size_t)N_NODES * 4);
  int* row_ptr  = (int*)alloc((size_t)(N_NODES + 1) * 4);
  int* cursor   = (int*)alloc((size_t)N_NODES * 4);
  int* bsum     = (int*)alloc((size_t)256 * 4);
  int* col_s    = (int*)alloc((size_t)N_EDGES * 4);
  float* val_s  = (float*)alloc((size_t)N_EDGES * 4);
  unsigned short* xA    = (unsigned short*)alloc((size_t)N_NODES * D * 2);
  unsigned short* xB    = (unsigned short*)alloc((size_t)N_NODES * D * 2);
  unsigned short* entbf = (unsigned short*)alloc((size_t)N_NODES * D * 2);
  unsigned short* ebf   = (unsigned short*)alloc((size_t)BATCH * KDIM * 2);
  unsigned short* Wt    = (unsigned short*)alloc((size_t)(N_ENT + 256) * KDIM * 2);  // pad rows
  unsigned short* Wt5   = (unsigned short*)alloc((size_t)N_LAYERS * D * D * 2);

  // CSR build (no coop kernels, no zero kernel)
  hipMemsetAsync(counts, 0, (size_t)N_NODES * 4, stream);
  hist_kernel<<<1024, 256, 0, stream>>>(edge_row, counts);
  scan1_kernel<<<SCAN_BLOCKS, 256, 0, stream>>>(counts, row_ptr, bsum);
  scan3_kernel<<<SCAN_BLOCKS, 256, 0, stream>>>(counts, bsum, row_ptr, cursor);
  scatter_kernel<<<1024, 256, 0, stream>>>(edge_row, edge_col, edge_val, cursor, col_s, val_s);

  // all conversions in one dispatch
  convert_all<<<CVT_A_BLOCKS + CVT_B_BLOCKS + CVT_C_BLOCKS, 256, 0, stream>>>(
      entity, gnn_W, fc_W, entbf, Wt5, Wt);

  // layers 0..3 full-graph, ping-pong: entbf->xA, xA->xB, xB->xA, xA->xB
  for (int layer = 0; layer < N_LAYERS - 1; ++layer) {
    const unsigned short* xin = (layer == 0) ? entbf : ((layer & 1) ? xA : xB);
    unsigned short* yout = (layer & 1) ? xB : xA;
    layer_fused<<<(N_NODES + 63) / 64, 256, 0, stream>>>(xin, row_ptr, col_s, val_s,
                                                         Wt5 + (size_t)layer * D * D,
                                                         gnn_b + (size_t)layer * D, yout);
  }

  // layer 4 head-rows-only + rel fill, fused: reads xB (layer-3 out), writes full ebf
  layer_head<<<BATCH / 64, 256, 0, stream>>>(xB, row_ptr, col_s, val_s, head_idx,
                                             rel_table, rel_ids,
                                             Wt5 + (size_t)(N_LAYERS - 1) * D * D,
                                             gnn_b + (size_t)(N_LAYERS - 1) * D, ebf);

  // FC: grid (n-tiles, b-halves)
  dim3 fcg((N_ENT + FC_NT - 1) / FC_NT, 2);
  fc_mfma<<<fcg, 256, 0, stream>>>(ebf, Wt, fc_b, out);
}